// Round 4
// baseline (692.676 us; speedup 1.0000x reference)
//
#include <hip/hip_runtime.h>

// GRU stack (L=6, H=2048, batch=1) + LayerNorm + Linear head. ALL fp32.
// ~620 MB of fp32 weights read once -> memory-bound, ~99 us roofline.
//
// R4: same fusion theory as R2/R3 (8 serialized dispatches suspected as
// the ~500 us overhead; two disjoint inner-loop structures both timed
// ~1 TB/s), but WITHOUT hipLaunchCooperativeKernel (suspect in the R3
// container hang under graph capture). Instead: plain launch of 256
// blocks x 512 thr (one per CU, all resident by construction) + a
// software grid barrier (device-scope atomic arrive + acquire spin) in
// d_ws, zeroed by a tiny init kernel each run. Monotone barrier targets
// 256*(l+1) -> no counter reset between layers.

constexpr int HID  = 2048;
constexpr int NL   = 6;
constexpr int G3   = 3 * HID;
constexpr int NBLK = 256;
constexpr int NTHR = 512;   // 8 waves

typedef float fx4 __attribute__((ext_vector_type(4)));

__device__ __forceinline__ float wave_sum(float s){
  #pragma unroll
  for(int off = 32; off; off >>= 1) s += __shfl_down(s, off, 64);
  return s;  // lane 0 holds total
}

__device__ __forceinline__ fx4 ntl(const float* p){
  return __builtin_nontemporal_load((const fx4*)p);
}

// device-scope grid barrier: all NBLK blocks arrive, spin until count>=target
__device__ __forceinline__ void gbar(unsigned* bar, unsigned target){
  __syncthreads();
  if(threadIdx.x == 0){
    __threadfence();   // make this block's buf writes visible device-wide
    __hip_atomic_fetch_add(bar, 1u, __ATOMIC_ACQ_REL, __HIP_MEMORY_SCOPE_AGENT);
    while(__hip_atomic_load(bar, __ATOMIC_ACQUIRE, __HIP_MEMORY_SCOPE_AGENT) < target)
      __builtin_amdgcn_s_sleep(2);
    __threadfence();   // invalidate stale cached lines before re-reading buf
  }
  __syncthreads();
}

__global__ void k_zero(unsigned* bar){ *bar = 0u; }

__global__ __launch_bounds__(NTHR) void k_fused(
    const float* __restrict__ x,
    const float* __restrict__ hidden,
    const float* __restrict__ w_ih,
    const float* __restrict__ w_hh,
    const float* __restrict__ b_ih,
    const float* __restrict__ b_hh,
    const float* __restrict__ gamma,
    const float* __restrict__ beta,
    const float* __restrict__ lin_w,
    const float* __restrict__ lin_b,
    float* __restrict__ out,    // [pred(2048) | new_hidden(6*2048)]
    float* __restrict__ buf,    // ws: activation chain, NL*HID floats
    unsigned* __restrict__ bar) // ws: grid-barrier counter
{
  __shared__ float vin[HID];            // layer input vector (8 KB)
  __shared__ float vh [HID];            // hidden state vector (8 KB)
  __shared__ float red[8], red2[8];
  __shared__ float s_mu, s_istd;

  const int tid  = threadIdx.x;
  const int wave = tid >> 6;
  const int lane = tid & 63;
  const int j    = blockIdx.x * 8 + wave;   // 0..2047, one j per wave

  for(int l = 0; l < NL; ++l){
    const float* inp = (l == 0) ? x : buf + (size_t)(l - 1) * HID;
    const float* hl  = hidden + (size_t)l * HID;

    // stage both vectors: 512 thr x one float4 each = 8 KB per vector
    ((float4*)vin)[tid] = ((const float4*)inp)[tid];
    ((float4*)vh )[tid] = ((const float4*)hl )[tid];
    __syncthreads();

    // 6 interleaved weight-row streams for output j
    const float* wib = w_ih + (size_t)l * G3 * HID + (size_t)j * HID;
    const float* whb = w_hh + (size_t)l * G3 * HID + (size_t)j * HID;
    const float* R0 = wib;
    const float* R1 = wib + (size_t)HID * HID;
    const float* R2 = wib + (size_t)2 * HID * HID;
    const float* R3 = whb;
    const float* R4 = whb + (size_t)HID * HID;
    const float* R5 = whb + (size_t)2 * HID * HID;
    const float4* A  = (const float4*)vin;
    const float4* Hh = (const float4*)vh;

    float a0 = 0.f, a1 = 0.f, a2 = 0.f, a3 = 0.f, a4 = 0.f, a5 = 0.f;
    #pragma unroll
    for(int it = 0; it < 8; ++it){
      const int idx = lane + 64 * it;
      const float4 va = A[idx];
      const float4 vb = Hh[idx];
      const fx4 w0 = ntl(R0 + 4 * idx);
      const fx4 w1 = ntl(R1 + 4 * idx);
      const fx4 w2 = ntl(R2 + 4 * idx);
      const fx4 w3 = ntl(R3 + 4 * idx);
      const fx4 w4 = ntl(R4 + 4 * idx);
      const fx4 w5 = ntl(R5 + 4 * idx);
      a0 += w0.x*va.x + w0.y*va.y + w0.z*va.z + w0.w*va.w;
      a1 += w1.x*va.x + w1.y*va.y + w1.z*va.z + w1.w*va.w;
      a2 += w2.x*va.x + w2.y*va.y + w2.z*va.z + w2.w*va.w;
      a3 += w3.x*vb.x + w3.y*vb.y + w3.z*vb.z + w3.w*vb.w;
      a4 += w4.x*vb.x + w4.y*vb.y + w4.z*vb.z + w4.w*vb.w;
      a5 += w5.x*vb.x + w5.y*vb.y + w5.z*vb.z + w5.w*vb.w;
    }

    const float g0 = wave_sum(a0);
    const float g1 = wave_sum(a1);
    const float g2 = wave_sum(a2);
    const float g3 = wave_sum(a3);
    const float g4 = wave_sum(a4);
    const float g5 = wave_sum(a5);

    if(lane == 0){
      const float* bi = b_ih + (size_t)l * G3;
      const float* bh = b_hh + (size_t)l * G3;
      float gi_r = g0 + bi[j];
      float gi_z = g1 + bi[HID + j];
      float gi_n = g2 + bi[2 * HID + j];
      float gh_r = g3 + bh[j];
      float gh_z = g4 + bh[HID + j];
      float gh_n = g5 + bh[2 * HID + j];
      float r = 1.f / (1.f + __expf(-(gi_r + gh_r)));
      float z = 1.f / (1.f + __expf(-(gi_z + gh_z)));
      float n = tanhf(gi_n + r * gh_n);
      float hn = (1.f - z) * n + z * vh[j];
      buf[(size_t)l * HID + j] = hn;          // next layer input
      out[HID + (size_t)l * HID + j] = hn;    // new_hidden output
    }
    gbar(bar, (unsigned)(NBLK * (l + 1)));
  }

  // ---- LayerNorm (computed redundantly per block, result in LDS) ----
  const float* htop = buf + (size_t)(NL - 1) * HID;
  {
    float s = 0.f, s2 = 0.f;
    for(int i = tid; i < HID; i += NTHR){ float v = htop[i]; s += v; s2 += v * v; }
    #pragma unroll
    for(int off = 32; off; off >>= 1){
      s  += __shfl_down(s,  off, 64);
      s2 += __shfl_down(s2, off, 64);
    }
    if(lane == 0){ red[wave] = s; red2[wave] = s2; }
    __syncthreads();
    if(tid == 0){
      float S = 0.f, S2 = 0.f;
      #pragma unroll
      for(int w = 0; w < 8; ++w){ S += red[w]; S2 += red2[w]; }
      float m   = S * (1.f / HID);
      float var = S2 * (1.f / HID) - m * m;
      s_mu = m; s_istd = rsqrtf(var + 1e-5f);
    }
    __syncthreads();
    const float mu = s_mu, istd = s_istd;
    for(int i = tid; i < HID; i += NTHR)
      vin[i] = (htop[i] - mu) * istd * gamma[i] + beta[i];
    __syncthreads();
  }

  // ---- Linear head: o = j, pred[o] = lin_w[o].ln + lin_b[o] + x[o] ----
  {
    const float* R  = lin_w + (size_t)j * HID;
    const float4* A = (const float4*)vin;
    float s = 0.f;
    #pragma unroll
    for(int it = 0; it < 8; ++it){
      const int idx = lane + 64 * it;
      const fx4 w = ntl(R + 4 * idx);
      const float4 a = A[idx];
      s += w.x*a.x + w.y*a.y + w.z*a.z + w.w*a.w;
    }
    s = wave_sum(s);
    if(lane == 0) out[j] = s + lin_b[j] + x[j];
  }
}

extern "C" void kernel_launch(void* const* d_in, const int* in_sizes, int n_in,
                              void* d_out, int out_size, void* d_ws, size_t ws_size,
                              hipStream_t stream){
  const float* x      = (const float*)d_in[0];
  const float* hidden = (const float*)d_in[1];
  const float* w_ih   = (const float*)d_in[2];
  const float* w_hh   = (const float*)d_in[3];
  const float* b_ih   = (const float*)d_in[4];
  const float* b_hh   = (const float*)d_in[5];
  const float* gamma  = (const float*)d_in[6];
  const float* beta   = (const float*)d_in[7];
  const float* lin_w  = (const float*)d_in[8];
  const float* lin_b  = (const float*)d_in[9];
  float* out = (float*)d_out;
  float* buf = (float*)d_ws;                                  // 6*HID floats
  unsigned* bar = (unsigned*)((char*)d_ws + (size_t)NL * HID * 4);  // 1 uint

  k_zero<<<1, 1, 0, stream>>>(bar);
  k_fused<<<NBLK, NTHR, 0, stream>>>(
      x, hidden, w_ih, w_hh, b_ih, b_hh, gamma, beta,
      lin_w, lin_b, out, buf, bar);
}